// Round 1
// baseline (477.849 us; speedup 1.0000x reference)
//
#include <hip/hip_runtime.h>
#include <hip/hip_bf16.h>
#include <math.h>

#define B_ 4096
#define I_ 1024
#define H_ 2048
#define K_ 3072   // I_ + H_
#define N4 8192   // 4 * H_
#define EPSGN 1e-5f

typedef __bf16 bf16;
typedef __bf16 bf16x4 __attribute__((ext_vector_type(4)));
typedef __bf16 bf16x8 __attribute__((ext_vector_type(8)));
typedef float  f32x4  __attribute__((ext_vector_type(4)));

// ---------------- fast activations (safe at extremes) ----------------
__device__ __forceinline__ float sigm(float x) {
  return 1.0f / (1.0f + __expf(-x));     // x->-inf: expf->inf -> 0; x->+inf: -> 1
}
__device__ __forceinline__ float tanh_fast(float x) {
  float a = fabsf(x);
  float e = __expf(-2.0f * a);           // e in (0,1], no overflow
  float t = (1.0f - e) / (1.0f + e);
  return copysignf(t, x);
}

// ---------------- convert A = [x | h_prev] -> bf16 [B_][K_] ----------------
__global__ void convA(const float* __restrict__ x, const float* __restrict__ h,
                      bf16* __restrict__ A) {
  long e = ((long)blockIdx.x * blockDim.x + threadIdx.x) * 4;
  if (e >= (long)B_ * K_) return;
  int b = (int)(e / K_);
  int k = (int)(e % K_);
  const float* src = (k < I_) ? (x + (long)b * I_ + k)
                              : (h + (long)b * H_ + (k - I_));
  f32x4 v = *(const f32x4*)src;
  bf16x4 o;
  o[0] = (bf16)v[0]; o[1] = (bf16)v[1]; o[2] = (bf16)v[2]; o[3] = (bf16)v[3];
  *(bf16x4*)(A + e) = o;
}

// ---------------- convert B^T = [Wg | Rg] per gate -> bf16 [N4][K_] ----------------
__global__ void convB(const float* __restrict__ Wi, const float* __restrict__ Wf,
                      const float* __restrict__ Wz, const float* __restrict__ Wo,
                      const float* __restrict__ Ri, const float* __restrict__ Rf,
                      const float* __restrict__ Rz, const float* __restrict__ Ro,
                      bf16* __restrict__ Bm) {
  long e = ((long)blockIdx.x * blockDim.x + threadIdx.x) * 4;
  if (e >= (long)N4 * K_) return;
  int g = (int)(e / ((long)H_ * K_));
  long rem = e % ((long)H_ * K_);
  int n = (int)(rem / K_);
  int k = (int)(rem % K_);
  const float* Wp = (g == 0) ? Wi : (g == 1) ? Wf : (g == 2) ? Wz : Wo;
  const float* Rp = (g == 0) ? Ri : (g == 1) ? Rf : (g == 2) ? Rz : Ro;
  const float* src = (k < I_) ? (Wp + (long)n * I_ + k)
                              : (Rp + (long)n * H_ + (k - I_));
  f32x4 v = *(const f32x4*)src;
  bf16x4 o;
  o[0] = (bf16)v[0]; o[1] = (bf16)v[1]; o[2] = (bf16)v[2]; o[3] = (bf16)v[3];
  *(bf16x4*)(Bm + e) = o;
}

// ---------------- GEMM: pre[B_][N4] = A[B_][K_] * Bm[N4][K_]^T ----------------
#define BM 128
#define BN 128
#define BK 32

__device__ __forceinline__ void gload16(const bf16* g, bf16* l) {
  __builtin_amdgcn_global_load_lds(
      (const __attribute__((address_space(1))) void*)g,
      (__attribute__((address_space(3))) void*)l, 16, 0, 0);
}

__global__ __launch_bounds__(256) void gemm_bt(const bf16* __restrict__ A,
                                               const bf16* __restrict__ Bm,
                                               float* __restrict__ pre) {
  __shared__ bf16 As[BM * BK];
  __shared__ bf16 Bs[BN * BK];

  // XCD-aware swizzle (2048 blocks, 2048 % 8 == 0 -> bijective)
  int bid = (blockIdx.x & 7) * 256 + (blockIdx.x >> 3);
  const int bidN = bid & 63;   // 64 N-tiles
  const int bidM = bid >> 6;   // 32 M-tiles

  const int t = threadIdx.x;
  const int lane = t & 63;
  const int wv = t >> 6;
  const int wm = wv >> 1;      // 2x2 waves of 64x64
  const int wn = wv & 1;

  // staging: thread t covers linear bf16 slots [8t, 8t+8) of each 128x32 tile
  const int sr = t >> 2;          // row 0..63
  const int sc = (t & 3) * 8;     // col 0,8,16,24
  const bf16* gA0 = A  + (long)(bidM * BM + sr)      * K_ + sc;
  const bf16* gA1 = A  + (long)(bidM * BM + sr + 64) * K_ + sc;
  const bf16* gB0 = Bm + (long)(bidN * BN + sr)      * K_ + sc;
  const bf16* gB1 = Bm + (long)(bidN * BN + sr + 64) * K_ + sc;
  bf16* lA0 = &As[sr * BK + sc];
  bf16* lA1 = &As[(sr + 64) * BK + sc];
  bf16* lB0 = &Bs[sr * BK + sc];
  bf16* lB1 = &Bs[(sr + 64) * BK + sc];

  f32x4 acc[4][4] = {};

  const int fr = lane & 15;          // fragment row (M for A, N for B)
  const int ko = (lane >> 4) * 8;    // K offset of this lane's 8 elems

  for (int k0 = 0; k0 < K_; k0 += BK) {
    gload16(gA0 + k0, lA0);
    gload16(gA1 + k0, lA1);
    gload16(gB0 + k0, lB0);
    gload16(gB1 + k0, lB1);
    __syncthreads();   // drains vmcnt -> LDS tiles ready

    bf16x8 af[4], bfr[4];
#pragma unroll
    for (int m = 0; m < 4; ++m)
      af[m] = *(const bf16x8*)(&As[(wm * 64 + m * 16 + fr) * BK + ko]);
#pragma unroll
    for (int n = 0; n < 4; ++n)
      bfr[n] = *(const bf16x8*)(&Bs[(wn * 64 + n * 16 + fr) * BK + ko]);
#pragma unroll
    for (int m = 0; m < 4; ++m)
#pragma unroll
      for (int n = 0; n < 4; ++n)
        acc[m][n] = __builtin_amdgcn_mfma_f32_16x16x32_bf16(af[m], bfr[n],
                                                            acc[m][n], 0, 0, 0);
    __syncthreads();   // protect LDS before next stage overwrites
  }

  // C/D layout (verified m89/m91): col = lane&15, row = (lane>>4)*4 + reg
  const int crow0 = (lane >> 4) * 4;
  const int ccol  = lane & 15;
#pragma unroll
  for (int m = 0; m < 4; ++m) {
#pragma unroll
    for (int n = 0; n < 4; ++n) {
#pragma unroll
      for (int j = 0; j < 4; ++j) {
        int row = bidM * BM + wm * 64 + m * 16 + crow0 + j;
        int col = bidN * BN + wn * 64 + n * 16 + ccol;
        pre[(long)row * N4 + col] = acc[m][n][j];
      }
    }
  }
}

// ---------------- elementwise: gates -> c, n, m (planes 1..3 of out) ----------------
__global__ void eltwise(const float* __restrict__ pre,
                        const float* __restrict__ bi, const float* __restrict__ bfp,
                        const float* __restrict__ bz, const float* __restrict__ bo,
                        const float* __restrict__ c_prev, const float* __restrict__ n_prev,
                        const float* __restrict__ m_prev,
                        float* __restrict__ out) {
  long e = ((long)blockIdx.x * blockDim.x + threadIdx.x) * 4;
  if (e >= (long)B_ * H_) return;
  int b = (int)(e / H_);
  int h = (int)(e % H_);
  const long PL = (long)B_ * H_;

  f32x4 PI = *(const f32x4*)(pre + (long)b * N4 + 0 * H_ + h);
  f32x4 PF = *(const f32x4*)(pre + (long)b * N4 + 1 * H_ + h);
  f32x4 PZ = *(const f32x4*)(pre + (long)b * N4 + 2 * H_ + h);
  f32x4 BI = *(const f32x4*)(bi + h);
  f32x4 BF = *(const f32x4*)(bfp + h);
  f32x4 BZ = *(const f32x4*)(bz + h);
  f32x4 CP = *(const f32x4*)(c_prev + e);
  f32x4 NP = *(const f32x4*)(n_prev + e);
  f32x4 MP = *(const f32x4*)(m_prev + e);

  f32x4 C, N, M;
#pragma unroll
  for (int j = 0; j < 4; ++j) {
    float ig = sigm(PI[j] + BI[j]);
    float fg = sigm(PF[j] + BF[j]);
    float zg = tanh_fast(PZ[j] + BZ[j]);
    M[j] = fmaxf(fg * MP[j], ig);
    C[j] = fg * CP[j] + ig * zg;
    N[j] = fg * NP[j] + ig;
  }
  *(f32x4*)(out + PL * 1 + e) = C;
  *(f32x4*)(out + PL * 2 + e) = N;
  *(f32x4*)(out + PL * 3 + e) = M;
  (void)bo;
}

// ---------------- GroupNorm(1) + output gate -> h (plane 0 of out) ----------------
__global__ __launch_bounds__(256) void gnorm(const float* __restrict__ pre,
                                             const float* __restrict__ bo,
                                             const float* __restrict__ gnw,
                                             const float* __restrict__ gnb,
                                             float* __restrict__ out) {
  const int b = blockIdx.x;
  const int t = threadIdx.x;
  const long PL = (long)B_ * H_;
  const float* crow = out + PL * 1 + (long)b * H_;
  const float* nrow = out + PL * 2 + (long)b * H_;

  float cs[8];
  float sum = 0.f, sq = 0.f;
#pragma unroll
  for (int j = 0; j < 8; ++j) {
    int hh = t + j * 256;
    float v = crow[hh] / nrow[hh];
    cs[j] = v;
    sum += v;
    sq  += v * v;
  }
#pragma unroll
  for (int off = 1; off < 64; off <<= 1) {
    sum += __shfl_xor(sum, off);
    sq  += __shfl_xor(sq, off);
  }
  __shared__ float s1[4], s2[4];
  const int wv = t >> 6, lane = t & 63;
  if (lane == 0) { s1[wv] = sum; s2[wv] = sq; }
  __syncthreads();
  sum = s1[0] + s1[1] + s1[2] + s1[3];
  sq  = s2[0] + s2[1] + s2[2] + s2[3];
  const float mu  = sum * (1.0f / H_);
  const float var = sq * (1.0f / H_) - mu * mu;
  const float rinv = rsqrtf(var + EPSGN);

#pragma unroll
  for (int j = 0; j < 8; ++j) {
    int hh = t + j * 256;
    float po = pre[(long)b * N4 + 3 * H_ + hh] + bo[hh];
    float o = sigm(po);
    float g = (cs[j] - mu) * rinv * gnw[hh] + gnb[hh];
    out[(long)b * H_ + hh] = o * tanh_fast(g);
  }
}

// ---------------- launch ----------------
extern "C" void kernel_launch(void* const* d_in, const int* in_sizes, int n_in,
                              void* d_out, int out_size, void* d_ws, size_t ws_size,
                              hipStream_t stream) {
  const float* x      = (const float*)d_in[0];
  const float* h_prev = (const float*)d_in[1];
  const float* c_prev = (const float*)d_in[2];
  const float* n_prev = (const float*)d_in[3];
  const float* m_prev = (const float*)d_in[4];
  const float* Wi = (const float*)d_in[5];
  const float* Wf = (const float*)d_in[6];
  const float* Wz = (const float*)d_in[7];
  const float* Wo = (const float*)d_in[8];
  const float* bi = (const float*)d_in[9];
  const float* bf = (const float*)d_in[10];
  const float* bz = (const float*)d_in[11];
  const float* bo = (const float*)d_in[12];
  const float* Ri = (const float*)d_in[13];
  const float* Rf = (const float*)d_in[14];
  const float* Rz = (const float*)d_in[15];
  const float* Ro = (const float*)d_in[16];
  const float* gnw = (const float*)d_in[17];
  const float* gnb = (const float*)d_in[18];

  char* ws = (char*)d_ws;
  bf16* Abf = (bf16*)ws;                                          // 24 MiB
  bf16* Bbf = (bf16*)(ws + (size_t)B_ * K_ * 2);                  // 48 MiB
  float* pre = (float*)(ws + (size_t)B_ * K_ * 2 + (size_t)N4 * K_ * 2);  // 128 MiB
  float* out = (float*)d_out;

  convA<<<(B_ * K_ / 4) / 256, 256, 0, stream>>>(x, h_prev, Abf);
  convB<<<((long)N4 * K_ / 4) / 256, 256, 0, stream>>>(Wi, Wf, Wz, Wo,
                                                       Ri, Rf, Rz, Ro, Bbf);
  gemm_bt<<<(B_ / BM) * (N4 / BN), 256, 0, stream>>>(Abf, Bbf, pre);
  eltwise<<<(B_ * H_ / 4) / 256, 256, 0, stream>>>(pre, bi, bf, bz, bo,
                                                   c_prev, n_prev, m_prev, out);
  gnorm<<<B_, 256, 0, stream>>>(pre, bo, gnw, gnb, out);
}

// Round 2
// 308.543 us; speedup vs baseline: 1.5487x; 1.5487x over previous
//
#include <hip/hip_runtime.h>
#include <hip/hip_bf16.h>
#include <math.h>

#define B_ 4096
#define I_ 1024
#define H_ 2048
#define K_ 3072   // I_ + H_
#define N4 8192   // 4 * H_
#define EPSGN 1e-5f

#define NT_K 48        // K_ / 64 k-tiles
#define PANB 16384     // bytes per 128x64 bf16 panel
#define LDSB 65536     // byte offset of B region in LDS

typedef __bf16 bf16;
typedef __bf16 bf16x8 __attribute__((ext_vector_type(8)));
typedef float  f32x4  __attribute__((ext_vector_type(4)));

__device__ __forceinline__ float sigm(float x) {
  return 1.0f / (1.0f + __expf(-x));
}
__device__ __forceinline__ float tanh_fast(float x) {
  float a = fabsf(x);
  float e = __expf(-2.0f * a);
  float t = (1.0f - e) / (1.0f + e);
  return copysignf(t, x);
}

// ---------- convA: [x|h_prev] -> tiled+swizzled bf16 panel images ----------
// A_t[mt(16)][kt(48)][half(2)][panel 16KB]; panel image:
// byte(r, ks) = r*128 + ((ks ^ (r&7))<<4), r in [0,128), ks in [0,8)
__global__ void convA(const float* __restrict__ x, const float* __restrict__ hp,
                      char* __restrict__ At) {
  int sid = blockIdx.x * blockDim.x + threadIdx.x;   // 16B slot id
  int p = sid & 1023;
  int pan = sid >> 10;              // 0..1535
  int mt = pan / 96;
  int rem = pan - mt * 96;
  int kt = rem >> 1;
  int h = rem & 1;
  int r = p >> 3;
  int ks = (p & 7) ^ (r & 7);       // logical k-slot (XOR is self-inverse)
  int row = mt * 256 + h * 128 + r;
  int k = kt * 64 + ks * 8;
  const float* src = (k < I_) ? (x + (size_t)row * I_ + k)
                              : (hp + (size_t)row * H_ + (k - I_));
  f32x4 v0 = *(const f32x4*)src;
  f32x4 v1 = *(const f32x4*)(src + 4);
  bf16x8 o;
  o[0]=(bf16)v0[0]; o[1]=(bf16)v0[1]; o[2]=(bf16)v0[2]; o[3]=(bf16)v0[3];
  o[4]=(bf16)v1[0]; o[5]=(bf16)v1[1]; o[6]=(bf16)v1[2]; o[7]=(bf16)v1[3];
  *(bf16x8*)(At + (size_t)sid * 16) = o;
}

// ---------- convB: [Wg|Rg] -> tiled+swizzled bf16 panel images ----------
// B_t[nt(32)][kt(48)][half(2)][panel 16KB]; col n = gate*2048 + h_idx
__global__ void convB(const float* __restrict__ Wi, const float* __restrict__ Wf,
                      const float* __restrict__ Wz, const float* __restrict__ Wo,
                      const float* __restrict__ Ri, const float* __restrict__ Rf,
                      const float* __restrict__ Rz, const float* __restrict__ Ro,
                      char* __restrict__ Bt) {
  int sid = blockIdx.x * blockDim.x + threadIdx.x;
  int p = sid & 1023;
  int pan = sid >> 10;              // 0..3071
  int nt = pan / 96;
  int rem = pan - nt * 96;
  int kt = rem >> 1;
  int h = rem & 1;
  int r = p >> 3;
  int ks = (p & 7) ^ (r & 7);
  int n = nt * 256 + h * 128 + r;
  int g = n >> 11;
  int hr = n & 2047;
  int k = kt * 64 + ks * 8;
  const float* Wp = (g == 0) ? Wi : (g == 1) ? Wf : (g == 2) ? Wz : Wo;
  const float* Rp = (g == 0) ? Ri : (g == 1) ? Rf : (g == 2) ? Rz : Ro;
  const float* src = (k < I_) ? (Wp + (size_t)hr * I_ + k)
                              : (Rp + (size_t)hr * H_ + (k - I_));
  f32x4 v0 = *(const f32x4*)src;
  f32x4 v1 = *(const f32x4*)(src + 4);
  bf16x8 o;
  o[0]=(bf16)v0[0]; o[1]=(bf16)v0[1]; o[2]=(bf16)v0[2]; o[3]=(bf16)v0[3];
  o[4]=(bf16)v1[0]; o[5]=(bf16)v1[1]; o[6]=(bf16)v1[2]; o[7]=(bf16)v1[3];
  *(bf16x8*)(Bt + (size_t)sid * 16) = o;
}

// ---------- 256x256 8-phase GEMM ----------
__device__ __forceinline__ void gload16(const char* g, char* l) {
  __builtin_amdgcn_global_load_lds(
      (const __attribute__((address_space(1))) void*)g,
      (__attribute__((address_space(3))) void*)l, 16, 0, 0);
}
__device__ __forceinline__ void stage(const char* g, char* l) {
  gload16(g, l);
  gload16(g + 8192, l + 8192);
}

__global__ __launch_bounds__(512, 2) void gemm8(const char* __restrict__ At,
                                                const char* __restrict__ Bt,
                                                float* __restrict__ pre) {
  extern __shared__ char lds[];
  const int tid = threadIdx.x;
  const int lane = tid & 63;
  const int wv = tid >> 6;       // 0..7
  const int wm = wv >> 2;        // 0..1  (A half = wm)
  const int wn = wv & 3;         // 0..3  (B half = wn>>1, sub = wn&1)

  // XCD swizzle: 512 blocks, 512 % 8 == 0 -> bijective
  int bid = (blockIdx.x & 7) * 64 + (blockIdx.x >> 3);
  const int bm = bid >> 5;       // 0..15
  const int bn = bid & 31;       // 0..31

  const char* a_src = At + (size_t)bm * (NT_K * 2 * PANB) + tid * 16;
  const char* b_src = Bt + (size_t)bn * (NT_K * 2 * PANB) + tid * 16;
  char* a_lds = lds + tid * 16;
  char* b_lds = lds + LDSB + tid * 16;

  // per-lane ds_read byte offsets (XOR-swizzled)
  const int l15 = lane & 15;
  const int l7  = lane & 7;
  const int q   = lane >> 4;
  int offk[2];
  offk[0] = l15 * 128 + (((0 + q) ^ l7) << 4);
  offk[1] = l15 * 128 + (((4 + q) ^ l7) << 4);

  const char* apan_base = lds + wm * PANB;                 // + parity*2*PANB
  const char* bpan_base = lds + LDSB + (wn >> 1) * PANB;
  const int bcol = (wn & 1) * 8192;

  f32x4 acc[8][4] = {};
  bf16x8 af[4][2], bfr[2][2][2];

  // ---- prologue: B(0)h0,h1  A(0)h0,h1  B(1)h0,h1 ----
  stage(b_src + 0 * PANB, b_lds + 0 * PANB);
  stage(b_src + 1 * PANB, b_lds + 1 * PANB);
  stage(a_src + 0 * PANB, a_lds + 0 * PANB);
  stage(a_src + 1 * PANB, a_lds + 1 * PANB);
  stage(b_src + 2 * PANB, b_lds + 2 * PANB);
  stage(b_src + 3 * PANB, b_lds + 3 * PANB);
  asm volatile("s_waitcnt vmcnt(4)" ::: "memory");   // tile0 panels landed
  __builtin_amdgcn_s_barrier();

#pragma unroll 2
  for (int t = 0; t < NT_K; ++t) {
    const int par = (t & 1) * 2;
    const char* apan = apan_base + par * PANB;
    const char* bpan = bpan_base + par * PANB;

    // ===== phase 0: quadrant (a=0, qn=0); stage Ah0(t+1) =====
#pragma unroll
    for (int fi = 0; fi < 4; ++fi)
#pragma unroll
      for (int ks = 0; ks < 2; ++ks)
        af[fi][ks] = *(const bf16x8*)(apan + fi * 2048 + offk[ks]);
#pragma unroll
    for (int fj = 0; fj < 2; ++fj)
#pragma unroll
      for (int ks = 0; ks < 2; ++ks)
        bfr[0][fj][ks] = *(const bf16x8*)(bpan + bcol + fj * 2048 + offk[ks]);
    if (t + 1 < NT_K)
      stage(a_src + (size_t)(t + 1) * 2 * PANB,
            a_lds + (((t + 1) & 1) * 2) * PANB);
    __builtin_amdgcn_s_barrier();
    asm volatile("s_waitcnt lgkmcnt(0)" ::: "memory");
    __builtin_amdgcn_s_setprio(1);
#pragma unroll
    for (int fi = 0; fi < 4; ++fi)
#pragma unroll
      for (int fj = 0; fj < 2; ++fj)
#pragma unroll
        for (int ks = 0; ks < 2; ++ks)
          acc[fi][fj] = __builtin_amdgcn_mfma_f32_16x16x32_bf16(
              af[fi][ks], bfr[0][fj][ks], acc[fi][fj], 0, 0, 0);
    __builtin_amdgcn_s_setprio(0);
    __builtin_amdgcn_s_barrier();

    // ===== phase 1: quadrant (a=0, qn=1); stage Ah1(t+1) =====
#pragma unroll
    for (int fj = 0; fj < 2; ++fj)
#pragma unroll
      for (int ks = 0; ks < 2; ++ks)
        bfr[1][fj][ks] = *(const bf16x8*)(bpan + bcol + 4096 + fj * 2048 + offk[ks]);
    if (t + 1 < NT_K)
      stage(a_src + (size_t)(t + 1) * 2 * PANB + PANB,
            a_lds + ((((t + 1) & 1) * 2) + 1) * PANB);
    __builtin_amdgcn_s_barrier();
    asm volatile("s_waitcnt lgkmcnt(0)" ::: "memory");
    __builtin_amdgcn_s_setprio(1);
#pragma unroll
    for (int fi = 0; fi < 4; ++fi)
#pragma unroll
      for (int fj = 0; fj < 2; ++fj)
#pragma unroll
        for (int ks = 0; ks < 2; ++ks)
          acc[fi][2 + fj] = __builtin_amdgcn_mfma_f32_16x16x32_bf16(
              af[fi][ks], bfr[1][fj][ks], acc[fi][2 + fj], 0, 0, 0);
    __builtin_amdgcn_s_setprio(0);
    __builtin_amdgcn_s_barrier();

    // ===== phase 2: quadrant (a=1, qn=1); stage Bh0(t+2) =====
#pragma unroll
    for (int fi = 0; fi < 4; ++fi)
#pragma unroll
      for (int ks = 0; ks < 2; ++ks)
        af[fi][ks] = *(const bf16x8*)(apan + 8192 + fi * 2048 + offk[ks]);
    if (t + 2 < NT_K)
      stage(b_src + (size_t)(t + 2) * 2 * PANB,
            b_lds + par * PANB);           // slotB(t+2,0) == par+0
    __builtin_amdgcn_s_barrier();
    asm volatile("s_waitcnt lgkmcnt(0)" ::: "memory");
    __builtin_amdgcn_s_setprio(1);
#pragma unroll
    for (int fi = 0; fi < 4; ++fi)
#pragma unroll
      for (int fj = 0; fj < 2; ++fj)
#pragma unroll
        for (int ks = 0; ks < 2; ++ks)
          acc[4 + fi][2 + fj] = __builtin_amdgcn_mfma_f32_16x16x32_bf16(
              af[fi][ks], bfr[1][fj][ks], acc[4 + fi][2 + fj], 0, 0, 0);
    __builtin_amdgcn_s_setprio(0);
    __builtin_amdgcn_s_barrier();

    // ===== phase 3: quadrant (a=1, qn=0); stage Bh1(t+2); boundary vmcnt =====
    if (t + 2 < NT_K)
      stage(b_src + (size_t)(t + 2) * 2 * PANB + PANB,
            b_lds + (par + 1) * PANB);     // slotB(t+2,1) == par+1
    __builtin_amdgcn_s_barrier();
    asm volatile("s_waitcnt lgkmcnt(0)" ::: "memory");
    __builtin_amdgcn_s_setprio(1);
#pragma unroll
    for (int fi = 0; fi < 4; ++fi)
#pragma unroll
      for (int fj = 0; fj < 2; ++fj)
#pragma unroll
        for (int ks = 0; ks < 2; ++ks)
          acc[4 + fi][fj] = __builtin_amdgcn_mfma_f32_16x16x32_bf16(
              af[fi][ks], bfr[0][fj][ks], acc[4 + fi][fj], 0, 0, 0);
    __builtin_amdgcn_s_setprio(0);
    if (t < NT_K - 2)
      asm volatile("s_waitcnt vmcnt(4)" ::: "memory");  // A(t+1) landed
    else
      asm volatile("s_waitcnt vmcnt(0)" ::: "memory");  // drain for last tiles
    __builtin_amdgcn_s_barrier();
  }

  // ---- epilogue: C-write (layout m89/m91: col=lane&15, row=(lane>>4)*4+j) ----
  const int crow0 = (lane >> 4) * 4;
  const int ccol  = lane & 15;
#pragma unroll
  for (int mi = 0; mi < 8; ++mi)
#pragma unroll
    for (int nj = 0; nj < 4; ++nj)
#pragma unroll
      for (int j = 0; j < 4; ++j) {
        int row = bm * 256 + wm * 128 + mi * 16 + crow0 + j;
        int col = bn * 256 + wn * 64 + nj * 16 + ccol;
        pre[(size_t)row * N4 + col] = acc[mi][nj][j];
      }
}

// ---------- elementwise: gates -> c, n, m ----------
__global__ void eltwise(const float* __restrict__ pre,
                        const float* __restrict__ bi, const float* __restrict__ bfp,
                        const float* __restrict__ bz, const float* __restrict__ bo,
                        const float* __restrict__ c_prev, const float* __restrict__ n_prev,
                        const float* __restrict__ m_prev,
                        float* __restrict__ out) {
  long e = ((long)blockIdx.x * blockDim.x + threadIdx.x) * 4;
  if (e >= (long)B_ * H_) return;
  int b = (int)(e / H_);
  int h = (int)(e % H_);
  const long PL = (long)B_ * H_;

  f32x4 PI = *(const f32x4*)(pre + (long)b * N4 + 0 * H_ + h);
  f32x4 PF = *(const f32x4*)(pre + (long)b * N4 + 1 * H_ + h);
  f32x4 PZ = *(const f32x4*)(pre + (long)b * N4 + 2 * H_ + h);
  f32x4 BI = *(const f32x4*)(bi + h);
  f32x4 BF = *(const f32x4*)(bfp + h);
  f32x4 BZ = *(const f32x4*)(bz + h);
  f32x4 CP = *(const f32x4*)(c_prev + e);
  f32x4 NP = *(const f32x4*)(n_prev + e);
  f32x4 MP = *(const f32x4*)(m_prev + e);

  f32x4 C, N, M;
#pragma unroll
  for (int j = 0; j < 4; ++j) {
    float ig = sigm(PI[j] + BI[j]);
    float fg = sigm(PF[j] + BF[j]);
    float zg = tanh_fast(PZ[j] + BZ[j]);
    M[j] = fmaxf(fg * MP[j], ig);
    C[j] = fg * CP[j] + ig * zg;
    N[j] = fg * NP[j] + ig;
  }
  *(f32x4*)(out + PL * 1 + e) = C;
  *(f32x4*)(out + PL * 2 + e) = N;
  *(f32x4*)(out + PL * 3 + e) = M;
  (void)bo;
}

// ---------- GroupNorm(1) + output gate -> h ----------
__global__ __launch_bounds__(256) void gnorm(const float* __restrict__ pre,
                                             const float* __restrict__ bo,
                                             const float* __restrict__ gnw,
                                             const float* __restrict__ gnb,
                                             float* __restrict__ out) {
  const int b = blockIdx.x;
  const int t = threadIdx.x;
  const long PL = (long)B_ * H_;
  const float* crow = out + PL * 1 + (long)b * H_;
  const float* nrow = out + PL * 2 + (long)b * H_;

  float cs[8];
  float sum = 0.f, sq = 0.f;
#pragma unroll
  for (int j = 0; j < 8; ++j) {
    int hh = t + j * 256;
    float v = crow[hh] / nrow[hh];
    cs[j] = v;
    sum += v;
    sq  += v * v;
  }
#pragma unroll
  for (int off = 1; off < 64; off <<= 1) {
    sum += __shfl_xor(sum, off);
    sq  += __shfl_xor(sq, off);
  }
  __shared__ float s1[4], s2[4];
  const int wv = t >> 6, lane = t & 63;
  if (lane == 0) { s1[wv] = sum; s2[wv] = sq; }
  __syncthreads();
  sum = s1[0] + s1[1] + s1[2] + s1[3];
  sq  = s2[0] + s2[1] + s2[2] + s2[3];
  const float mu  = sum * (1.0f / H_);
  const float var = sq * (1.0f / H_) - mu * mu;
  const float rinv = rsqrtf(var + EPSGN);

#pragma unroll
  for (int j = 0; j < 8; ++j) {
    int hh = t + j * 256;
    float po = pre[(long)b * N4 + 3 * H_ + hh] + bo[hh];
    float o = sigm(po);
    float g = (cs[j] - mu) * rinv * gnw[hh] + gnb[hh];
    out[(long)b * H_ + hh] = o * tanh_fast(g);
  }
}

// ---------- launch ----------
extern "C" void kernel_launch(void* const* d_in, const int* in_sizes, int n_in,
                              void* d_out, int out_size, void* d_ws, size_t ws_size,
                              hipStream_t stream) {
  const float* x      = (const float*)d_in[0];
  const float* h_prev = (const float*)d_in[1];
  const float* c_prev = (const float*)d_in[2];
  const float* n_prev = (const float*)d_in[3];
  const float* m_prev = (const float*)d_in[4];
  const float* Wi = (const float*)d_in[5];
  const float* Wf = (const float*)d_in[6];
  const float* Wz = (const float*)d_in[7];
  const float* Wo = (const float*)d_in[8];
  const float* bi = (const float*)d_in[9];
  const float* bf = (const float*)d_in[10];
  const float* bz = (const float*)d_in[11];
  const float* bo = (const float*)d_in[12];
  const float* Ri = (const float*)d_in[13];
  const float* Rf = (const float*)d_in[14];
  const float* Rz = (const float*)d_in[15];
  const float* Ro = (const float*)d_in[16];
  const float* gnw = (const float*)d_in[17];
  const float* gnb = (const float*)d_in[18];

  char* ws = (char*)d_ws;
  char* At = ws;                                             // 24 MiB
  char* Bt = ws + (size_t)B_ * K_ * 2;                       // 48 MiB
  float* pre = (float*)(ws + (size_t)B_ * K_ * 2 + (size_t)N4 * K_ * 2);  // 128 MiB
  float* out = (float*)d_out;

  static bool attr_set = false;
  (void)attr_set;
  hipFuncSetAttribute((const void*)gemm8,
                      hipFuncAttributeMaxDynamicSharedMemorySize, 131072);

  convA<<<((size_t)B_ * K_ / 8) / 256, 256, 0, stream>>>(x, h_prev, At);
  convB<<<((size_t)N4 * K_ / 8) / 256, 256, 0, stream>>>(Wi, Wf, Wz, Wo,
                                                         Ri, Rf, Rz, Ro, Bt);
  gemm8<<<512, 512, 131072, stream>>>(At, Bt, pre);
  eltwise<<<(B_ * H_ / 4) / 256, 256, 0, stream>>>(pre, bi, bf, bz, bo,
                                                   c_prev, n_prev, m_prev, out);
  gnorm<<<B_, 256, 0, stream>>>(pre, bo, gnw, gnb, out);
}

// Round 3
// 290.094 us; speedup vs baseline: 1.6472x; 1.0636x over previous
//
#include <hip/hip_runtime.h>
#include <hip/hip_bf16.h>
#include <math.h>

#define B_ 4096
#define I_ 1024
#define H_ 2048
#define K_ 3072   // I_ + H_
#define N4 8192   // 4 * H_
#define EPSGN 1e-5f

#define NT_K 48        // K_ / 64 k-tiles
#define PANB 16384     // bytes per 128x64 bf16 panel
#define LDSB 65536     // byte offset of B region in LDS

typedef __bf16 bf16;
typedef __bf16 bf16x8 __attribute__((ext_vector_type(8)));
typedef float  f32x4  __attribute__((ext_vector_type(4)));

__device__ __forceinline__ float sigm(float x) {
  return 1.0f / (1.0f + __expf(-x));
}
__device__ __forceinline__ float tanh_fast(float x) {
  float a = fabsf(x);
  float e = __expf(-2.0f * a);
  float t = (1.0f - e) / (1.0f + e);
  return copysignf(t, x);
}

// ---------- convA: [x|h_prev] -> tiled+swizzled bf16 panel images ----------
// A_t[mt(16)][kt(48)][half(2)][panel 16KB]; panel image:
// byte(r, ks) = r*128 + ((ks ^ (r&7))<<4), r in [0,128), ks in [0,8)
__global__ void convA(const float* __restrict__ x, const float* __restrict__ hp,
                      char* __restrict__ At) {
  int sid = blockIdx.x * blockDim.x + threadIdx.x;   // 16B slot id
  int p = sid & 1023;
  int pan = sid >> 10;              // 0..1535
  int mt = pan / 96;
  int rem = pan - mt * 96;
  int kt = rem >> 1;
  int h = rem & 1;
  int r = p >> 3;
  int ks = (p & 7) ^ (r & 7);       // logical k-slot (XOR is self-inverse)
  int row = mt * 256 + h * 128 + r;
  int k = kt * 64 + ks * 8;
  const float* src = (k < I_) ? (x + (size_t)row * I_ + k)
                              : (hp + (size_t)row * H_ + (k - I_));
  f32x4 v0 = *(const f32x4*)src;
  f32x4 v1 = *(const f32x4*)(src + 4);
  bf16x8 o;
  o[0]=(bf16)v0[0]; o[1]=(bf16)v0[1]; o[2]=(bf16)v0[2]; o[3]=(bf16)v0[3];
  o[4]=(bf16)v1[0]; o[5]=(bf16)v1[1]; o[6]=(bf16)v1[2]; o[7]=(bf16)v1[3];
  *(bf16x8*)(At + (size_t)sid * 16) = o;
}

// ---------- convB: [Wg|Rg] -> tiled+swizzled bf16 panel images ----------
__global__ void convB(const float* __restrict__ Wi, const float* __restrict__ Wf,
                      const float* __restrict__ Wz, const float* __restrict__ Wo,
                      const float* __restrict__ Ri, const float* __restrict__ Rf,
                      const float* __restrict__ Rz, const float* __restrict__ Ro,
                      char* __restrict__ Bt) {
  int sid = blockIdx.x * blockDim.x + threadIdx.x;
  int p = sid & 1023;
  int pan = sid >> 10;              // 0..3071
  int nt = pan / 96;
  int rem = pan - nt * 96;
  int kt = rem >> 1;
  int h = rem & 1;
  int r = p >> 3;
  int ks = (p & 7) ^ (r & 7);
  int n = nt * 256 + h * 128 + r;
  int g = n >> 11;
  int hr = n & 2047;
  int k = kt * 64 + ks * 8;
  const float* Wp = (g == 0) ? Wi : (g == 1) ? Wf : (g == 2) ? Wz : Wo;
  const float* Rp = (g == 0) ? Ri : (g == 1) ? Rf : (g == 2) ? Rz : Ro;
  const float* src = (k < I_) ? (Wp + (size_t)hr * I_ + k)
                              : (Rp + (size_t)hr * H_ + (k - I_));
  f32x4 v0 = *(const f32x4*)src;
  f32x4 v1 = *(const f32x4*)(src + 4);
  bf16x8 o;
  o[0]=(bf16)v0[0]; o[1]=(bf16)v0[1]; o[2]=(bf16)v0[2]; o[3]=(bf16)v0[3];
  o[4]=(bf16)v1[0]; o[5]=(bf16)v1[1]; o[6]=(bf16)v1[2]; o[7]=(bf16)v1[3];
  *(bf16x8*)(Bt + (size_t)sid * 16) = o;
}

// ---------- 256x256 8-phase GEMM (pre output in bf16) ----------
__device__ __forceinline__ void gload16(const char* g, char* l) {
  __builtin_amdgcn_global_load_lds(
      (const __attribute__((address_space(1))) void*)g,
      (__attribute__((address_space(3))) void*)l, 16, 0, 0);
}
__device__ __forceinline__ void stage(const char* g, char* l) {
  gload16(g, l);
  gload16(g + 8192, l + 8192);
}

__global__ __launch_bounds__(512, 2) void gemm8(const char* __restrict__ At,
                                                const char* __restrict__ Bt,
                                                bf16* __restrict__ pre) {
  extern __shared__ char lds[];
  const int tid = threadIdx.x;
  const int lane = tid & 63;
  const int wv = tid >> 6;       // 0..7
  const int wm = wv >> 2;        // 0..1  (A half = wm)
  const int wn = wv & 3;         // 0..3  (B half = wn>>1, sub = wn&1)

  // XCD swizzle: 512 blocks, 512 % 8 == 0 -> bijective
  int bid = (blockIdx.x & 7) * 64 + (blockIdx.x >> 3);
  const int bm = bid >> 5;       // 0..15
  const int bn = bid & 31;       // 0..31

  const char* a_src = At + (size_t)bm * (NT_K * 2 * PANB) + tid * 16;
  const char* b_src = Bt + (size_t)bn * (NT_K * 2 * PANB) + tid * 16;
  char* a_lds = lds + tid * 16;
  char* b_lds = lds + LDSB + tid * 16;

  // per-lane ds_read byte offsets (XOR-swizzled)
  const int l15 = lane & 15;
  const int l7  = lane & 7;
  const int q   = lane >> 4;
  int offk[2];
  offk[0] = l15 * 128 + (((0 + q) ^ l7) << 4);
  offk[1] = l15 * 128 + (((4 + q) ^ l7) << 4);

  const char* apan_base = lds + wm * PANB;                 // + parity*2*PANB
  const char* bpan_base = lds + LDSB + (wn >> 1) * PANB;
  const int bcol = (wn & 1) * 8192;

  f32x4 acc[8][4] = {};
  bf16x8 af[4][2], bfr[2][2][2];

  // ---- prologue: B(0)h0,h1  A(0)h0,h1  B(1)h0,h1 ----
  stage(b_src + 0 * PANB, b_lds + 0 * PANB);
  stage(b_src + 1 * PANB, b_lds + 1 * PANB);
  stage(a_src + 0 * PANB, a_lds + 0 * PANB);
  stage(a_src + 1 * PANB, a_lds + 1 * PANB);
  stage(b_src + 2 * PANB, b_lds + 2 * PANB);
  stage(b_src + 3 * PANB, b_lds + 3 * PANB);
  asm volatile("s_waitcnt vmcnt(4)" ::: "memory");   // tile0 panels landed
  __builtin_amdgcn_s_barrier();

#pragma unroll 2
  for (int t = 0; t < NT_K; ++t) {
    const int par = (t & 1) * 2;
    const char* apan = apan_base + par * PANB;
    const char* bpan = bpan_base + par * PANB;

    // ===== phase 0: quadrant (a=0, qn=0); stage Ah0(t+1) =====
#pragma unroll
    for (int fi = 0; fi < 4; ++fi)
#pragma unroll
      for (int ks = 0; ks < 2; ++ks)
        af[fi][ks] = *(const bf16x8*)(apan + fi * 2048 + offk[ks]);
#pragma unroll
    for (int fj = 0; fj < 2; ++fj)
#pragma unroll
      for (int ks = 0; ks < 2; ++ks)
        bfr[0][fj][ks] = *(const bf16x8*)(bpan + bcol + fj * 2048 + offk[ks]);
    if (t + 1 < NT_K)
      stage(a_src + (size_t)(t + 1) * 2 * PANB,
            a_lds + (((t + 1) & 1) * 2) * PANB);
    __builtin_amdgcn_s_barrier();
    asm volatile("s_waitcnt lgkmcnt(0)" ::: "memory");
    __builtin_amdgcn_s_setprio(1);
#pragma unroll
    for (int fi = 0; fi < 4; ++fi)
#pragma unroll
      for (int fj = 0; fj < 2; ++fj)
#pragma unroll
        for (int ks = 0; ks < 2; ++ks)
          acc[fi][fj] = __builtin_amdgcn_mfma_f32_16x16x32_bf16(
              af[fi][ks], bfr[0][fj][ks], acc[fi][fj], 0, 0, 0);
    __builtin_amdgcn_s_setprio(0);
    __builtin_amdgcn_s_barrier();

    // ===== phase 1: quadrant (a=0, qn=1); stage Ah1(t+1) =====
#pragma unroll
    for (int fj = 0; fj < 2; ++fj)
#pragma unroll
      for (int ks = 0; ks < 2; ++ks)
        bfr[1][fj][ks] = *(const bf16x8*)(bpan + bcol + 4096 + fj * 2048 + offk[ks]);
    if (t + 1 < NT_K)
      stage(a_src + (size_t)(t + 1) * 2 * PANB + PANB,
            a_lds + ((((t + 1) & 1) * 2) + 1) * PANB);
    __builtin_amdgcn_s_barrier();
    asm volatile("s_waitcnt lgkmcnt(0)" ::: "memory");
    __builtin_amdgcn_s_setprio(1);
#pragma unroll
    for (int fi = 0; fi < 4; ++fi)
#pragma unroll
      for (int fj = 0; fj < 2; ++fj)
#pragma unroll
        for (int ks = 0; ks < 2; ++ks)
          acc[fi][2 + fj] = __builtin_amdgcn_mfma_f32_16x16x32_bf16(
              af[fi][ks], bfr[1][fj][ks], acc[fi][2 + fj], 0, 0, 0);
    __builtin_amdgcn_s_setprio(0);
    __builtin_amdgcn_s_barrier();

    // ===== phase 2: quadrant (a=1, qn=1); stage Bh0(t+2) =====
#pragma unroll
    for (int fi = 0; fi < 4; ++fi)
#pragma unroll
      for (int ks = 0; ks < 2; ++ks)
        af[fi][ks] = *(const bf16x8*)(apan + 8192 + fi * 2048 + offk[ks]);
    if (t + 2 < NT_K)
      stage(b_src + (size_t)(t + 2) * 2 * PANB,
            b_lds + par * PANB);           // slotB(t+2,0) == par+0
    __builtin_amdgcn_s_barrier();
    asm volatile("s_waitcnt lgkmcnt(0)" ::: "memory");
    __builtin_amdgcn_s_setprio(1);
#pragma unroll
    for (int fi = 0; fi < 4; ++fi)
#pragma unroll
      for (int fj = 0; fj < 2; ++fj)
#pragma unroll
        for (int ks = 0; ks < 2; ++ks)
          acc[4 + fi][2 + fj] = __builtin_amdgcn_mfma_f32_16x16x32_bf16(
              af[fi][ks], bfr[1][fj][ks], acc[4 + fi][2 + fj], 0, 0, 0);
    __builtin_amdgcn_s_setprio(0);
    __builtin_amdgcn_s_barrier();

    // ===== phase 3: quadrant (a=1, qn=0); stage Bh1(t+2); boundary vmcnt =====
    if (t + 2 < NT_K)
      stage(b_src + (size_t)(t + 2) * 2 * PANB + PANB,
            b_lds + (par + 1) * PANB);     // slotB(t+2,1) == par+1
    __builtin_amdgcn_s_barrier();
    asm volatile("s_waitcnt lgkmcnt(0)" ::: "memory");
    __builtin_amdgcn_s_setprio(1);
#pragma unroll
    for (int fi = 0; fi < 4; ++fi)
#pragma unroll
      for (int fj = 0; fj < 2; ++fj)
#pragma unroll
        for (int ks = 0; ks < 2; ++ks)
          acc[4 + fi][fj] = __builtin_amdgcn_mfma_f32_16x16x32_bf16(
              af[fi][ks], bfr[0][fj][ks], acc[4 + fi][fj], 0, 0, 0);
    __builtin_amdgcn_s_setprio(0);
    if (t < NT_K - 2)
      asm volatile("s_waitcnt vmcnt(4)" ::: "memory");  // A(t+1) landed
    else
      asm volatile("s_waitcnt vmcnt(0)" ::: "memory");  // drain for last tiles
    __builtin_amdgcn_s_barrier();
  }

  // ---- epilogue: bf16 C-write (layout m89/m91: col=lane&15, row=(lane>>4)*4+j) ----
  const int crow0 = (lane >> 4) * 4;
  const int ccol  = lane & 15;
#pragma unroll
  for (int mi = 0; mi < 8; ++mi)
#pragma unroll
    for (int nj = 0; nj < 4; ++nj)
#pragma unroll
      for (int j = 0; j < 4; ++j) {
        int row = bm * 256 + wm * 128 + mi * 16 + crow0 + j;
        int col = bn * 256 + wn * 64 + nj * 16 + ccol;
        pre[(size_t)row * N4 + col] = (bf16)acc[mi][nj][j];
      }
}

// ---------- fused pointwise + GroupNorm: one block per batch row ----------
__global__ __launch_bounds__(256) void fusedpost(
    const bf16* __restrict__ pre,
    const float* __restrict__ bi, const float* __restrict__ bfp,
    const float* __restrict__ bz, const float* __restrict__ bo,
    const float* __restrict__ c_prev, const float* __restrict__ n_prev,
    const float* __restrict__ m_prev,
    const float* __restrict__ gnw, const float* __restrict__ gnb,
    float* __restrict__ out) {
  const int b = blockIdx.x;
  const int t = threadIdx.x;
  const int h0 = t * 8;
  const long PL = (long)B_ * H_;
  const long e = (long)b * H_ + h0;
  const bf16* prow = pre + (size_t)b * N4;

  bf16x8 PI = *(const bf16x8*)(prow + 0 * H_ + h0);
  bf16x8 PF = *(const bf16x8*)(prow + 1 * H_ + h0);
  bf16x8 PZ = *(const bf16x8*)(prow + 2 * H_ + h0);
  bf16x8 PO = *(const bf16x8*)(prow + 3 * H_ + h0);
  f32x4 BI0 = *(const f32x4*)(bi + h0),  BI1 = *(const f32x4*)(bi + h0 + 4);
  f32x4 BF0 = *(const f32x4*)(bfp + h0), BF1 = *(const f32x4*)(bfp + h0 + 4);
  f32x4 BZ0 = *(const f32x4*)(bz + h0),  BZ1 = *(const f32x4*)(bz + h0 + 4);
  f32x4 BO0 = *(const f32x4*)(bo + h0),  BO1 = *(const f32x4*)(bo + h0 + 4);
  f32x4 CP0 = *(const f32x4*)(c_prev + e), CP1 = *(const f32x4*)(c_prev + e + 4);
  f32x4 NP0 = *(const f32x4*)(n_prev + e), NP1 = *(const f32x4*)(n_prev + e + 4);
  f32x4 MP0 = *(const f32x4*)(m_prev + e), MP1 = *(const f32x4*)(m_prev + e + 4);

  float cs[8], og[8];
  f32x4 C0, C1, N0, N1, M0, M1;
  float sum = 0.f, sq = 0.f;
#pragma unroll
  for (int j = 0; j < 8; ++j) {
    float pi = (float)PI[j] + ((j < 4) ? BI0[j] : BI1[j - 4]);
    float pf = (float)PF[j] + ((j < 4) ? BF0[j] : BF1[j - 4]);
    float pz = (float)PZ[j] + ((j < 4) ? BZ0[j] : BZ1[j - 4]);
    float po = (float)PO[j] + ((j < 4) ? BO0[j] : BO1[j - 4]);
    float cp = (j < 4) ? CP0[j] : CP1[j - 4];
    float np = (j < 4) ? NP0[j] : NP1[j - 4];
    float mp = (j < 4) ? MP0[j] : MP1[j - 4];
    float ig = sigm(pi);
    float fg = sigm(pf);
    float zg = tanh_fast(pz);
    og[j] = sigm(po);
    float m = fmaxf(fg * mp, ig);
    float c = fg * cp + ig * zg;
    float n = fg * np + ig;
    if (j < 4) { C0[j] = c; N0[j] = n; M0[j] = m; }
    else       { C1[j-4] = c; N1[j-4] = n; M1[j-4] = m; }
    float v = c / n;
    cs[j] = v;
    sum += v;
    sq  += v * v;
  }
  *(f32x4*)(out + PL * 1 + e) = C0; *(f32x4*)(out + PL * 1 + e + 4) = C1;
  *(f32x4*)(out + PL * 2 + e) = N0; *(f32x4*)(out + PL * 2 + e + 4) = N1;
  *(f32x4*)(out + PL * 3 + e) = M0; *(f32x4*)(out + PL * 3 + e + 4) = M1;

#pragma unroll
  for (int off = 1; off < 64; off <<= 1) {
    sum += __shfl_xor(sum, off);
    sq  += __shfl_xor(sq, off);
  }
  __shared__ float s1[4], s2[4];
  const int wv = t >> 6, lane = t & 63;
  if (lane == 0) { s1[wv] = sum; s2[wv] = sq; }
  __syncthreads();
  sum = s1[0] + s1[1] + s1[2] + s1[3];
  sq  = s2[0] + s2[1] + s2[2] + s2[3];
  const float mu  = sum * (1.0f / H_);
  const float var = sq * (1.0f / H_) - mu * mu;
  const float rinv = rsqrtf(var + EPSGN);

  f32x4 GW0 = *(const f32x4*)(gnw + h0), GW1 = *(const f32x4*)(gnw + h0 + 4);
  f32x4 GB0 = *(const f32x4*)(gnb + h0), GB1 = *(const f32x4*)(gnb + h0 + 4);
  f32x4 Hh0, Hh1;
#pragma unroll
  for (int j = 0; j < 8; ++j) {
    float gw = (j < 4) ? GW0[j] : GW1[j - 4];
    float gb = (j < 4) ? GB0[j] : GB1[j - 4];
    float g = (cs[j] - mu) * rinv * gw + gb;
    float hv = og[j] * tanh_fast(g);
    if (j < 4) Hh0[j] = hv; else Hh1[j - 4] = hv;
  }
  *(f32x4*)(out + e) = Hh0;
  *(f32x4*)(out + e + 4) = Hh1;
}

// ---------- launch ----------
extern "C" void kernel_launch(void* const* d_in, const int* in_sizes, int n_in,
                              void* d_out, int out_size, void* d_ws, size_t ws_size,
                              hipStream_t stream) {
  const float* x      = (const float*)d_in[0];
  const float* h_prev = (const float*)d_in[1];
  const float* c_prev = (const float*)d_in[2];
  const float* n_prev = (const float*)d_in[3];
  const float* m_prev = (const float*)d_in[4];
  const float* Wi = (const float*)d_in[5];
  const float* Wf = (const float*)d_in[6];
  const float* Wz = (const float*)d_in[7];
  const float* Wo = (const float*)d_in[8];
  const float* bi = (const float*)d_in[9];
  const float* bf = (const float*)d_in[10];
  const float* bz = (const float*)d_in[11];
  const float* bo = (const float*)d_in[12];
  const float* Ri = (const float*)d_in[13];
  const float* Rf = (const float*)d_in[14];
  const float* Rz = (const float*)d_in[15];
  const float* Ro = (const float*)d_in[16];
  const float* gnw = (const float*)d_in[17];
  const float* gnb = (const float*)d_in[18];

  char* ws = (char*)d_ws;
  char* At = ws;                                             // 24 MiB
  char* Bt = ws + (size_t)B_ * K_ * 2;                       // 48 MiB
  bf16* pre = (bf16*)(ws + (size_t)B_ * K_ * 2 + (size_t)N4 * K_ * 2);  // 64 MiB
  float* out = (float*)d_out;

  hipFuncSetAttribute((const void*)gemm8,
                      hipFuncAttributeMaxDynamicSharedMemorySize, 131072);

  convA<<<((size_t)B_ * K_ / 8) / 256, 256, 0, stream>>>(x, h_prev, At);
  convB<<<((size_t)N4 * K_ / 8) / 256, 256, 0, stream>>>(Wi, Wf, Wz, Wo,
                                                         Ri, Rf, Rz, Ro, Bt);
  gemm8<<<512, 512, 131072, stream>>>(At, Bt, pre);
  fusedpost<<<B_, 256, 0, stream>>>(pre, bi, bf, bz, bo,
                                    c_prev, n_prev, m_prev, gnw, gnb, out);
}

// Round 5
// 286.802 us; speedup vs baseline: 1.6661x; 1.0115x over previous
//
#include <hip/hip_runtime.h>
#include <hip/hip_bf16.h>
#include <math.h>

#define B_ 4096
#define I_ 1024
#define H_ 2048
#define K_ 3072   // I_ + H_
#define N4 8192   // 4 * H_
#define EPSGN 1e-5f

#define NT_K 48        // K_ / 64 k-tiles
#define PANB 16384     // bytes per 128x64 bf16 panel
#define LDSB 65536     // byte offset of B region in LDS

typedef __bf16 bf16;
typedef __bf16 bf16x8 __attribute__((ext_vector_type(8)));
typedef float  f32x4  __attribute__((ext_vector_type(4)));

__device__ __forceinline__ float sigm(float x) {
  return 1.0f / (1.0f + __expf(-x));
}
__device__ __forceinline__ float tanh_fast(float x) {
  float a = fabsf(x);
  float e = __expf(-2.0f * a);
  float t = (1.0f - e) / (1.0f + e);
  return copysignf(t, x);
}

// ---------- convA: [x|h_prev] -> tiled+swizzled bf16 panel images ----------
// A_t[mt(16)][kt(48)][half(2)][panel 16KB]; panel image:
// byte(r, ks) = r*128 + ((ks ^ (r&7))<<4), r in [0,128), ks in [0,8)
__global__ void convA(const float* __restrict__ x, const float* __restrict__ hp,
                      char* __restrict__ At) {
  int sid = blockIdx.x * blockDim.x + threadIdx.x;   // 16B slot id
  int p = sid & 1023;
  int pan = sid >> 10;              // 0..1535
  int mt = pan / 96;
  int rem = pan - mt * 96;
  int kt = rem >> 1;
  int h = rem & 1;
  int r = p >> 3;
  int ks = (p & 7) ^ (r & 7);       // logical k-slot (XOR is self-inverse)
  int row = mt * 256 + h * 128 + r;
  int k = kt * 64 + ks * 8;
  const float* src = (k < I_) ? (x + (size_t)row * I_ + k)
                              : (hp + (size_t)row * H_ + (k - I_));
  f32x4 v0 = *(const f32x4*)src;
  f32x4 v1 = *(const f32x4*)(src + 4);
  bf16x8 o;
  o[0]=(bf16)v0[0]; o[1]=(bf16)v0[1]; o[2]=(bf16)v0[2]; o[3]=(bf16)v0[3];
  o[4]=(bf16)v1[0]; o[5]=(bf16)v1[1]; o[6]=(bf16)v1[2]; o[7]=(bf16)v1[3];
  *(bf16x8*)(At + (size_t)sid * 16) = o;
}

// ---------- convB: [Wg|Rg] -> tiled+swizzled bf16 panel images ----------
__global__ void convB(const float* __restrict__ Wi, const float* __restrict__ Wf,
                      const float* __restrict__ Wz, const float* __restrict__ Wo,
                      const float* __restrict__ Ri, const float* __restrict__ Rf,
                      const float* __restrict__ Rz, const float* __restrict__ Ro,
                      char* __restrict__ Bt) {
  int sid = blockIdx.x * blockDim.x + threadIdx.x;
  int p = sid & 1023;
  int pan = sid >> 10;              // 0..3071
  int nt = pan / 96;
  int rem = pan - nt * 96;
  int kt = rem >> 1;
  int h = rem & 1;
  int r = p >> 3;
  int ks = (p & 7) ^ (r & 7);
  int n = nt * 256 + h * 128 + r;
  int g = n >> 11;
  int hr = n & 2047;
  int k = kt * 64 + ks * 8;
  const float* Wp = (g == 0) ? Wi : (g == 1) ? Wf : (g == 2) ? Wz : Wo;
  const float* Rp = (g == 0) ? Ri : (g == 1) ? Rf : (g == 2) ? Rz : Ro;
  const float* src = (k < I_) ? (Wp + (size_t)hr * I_ + k)
                              : (Rp + (size_t)hr * H_ + (k - I_));
  f32x4 v0 = *(const f32x4*)src;
  f32x4 v1 = *(const f32x4*)(src + 4);
  bf16x8 o;
  o[0]=(bf16)v0[0]; o[1]=(bf16)v0[1]; o[2]=(bf16)v0[2]; o[3]=(bf16)v0[3];
  o[4]=(bf16)v1[0]; o[5]=(bf16)v1[1]; o[6]=(bf16)v1[2]; o[7]=(bf16)v1[3];
  *(bf16x8*)(Bt + (size_t)sid * 16) = o;
}

// ---------- 256x256 GEMM, 4 phases/ktile, shadow ds_reads, 1 bar/phase ----------
__device__ __forceinline__ void gload16(const char* g, char* l) {
  __builtin_amdgcn_global_load_lds(
      (const __attribute__((address_space(1))) void*)g,
      (__attribute__((address_space(3))) void*)l, 16, 0, 0);
}
__device__ __forceinline__ void stage(const char* g, char* l) {
  gload16(g, l);
  gload16(g + 8192, l + 8192);
}

__global__ __launch_bounds__(512, 2) void gemm8(const char* __restrict__ At,
                                                const char* __restrict__ Bt,
                                                bf16* __restrict__ pre) {
  extern __shared__ char lds[];
  const int tid = threadIdx.x;
  const int lane = tid & 63;
  const int wv = tid >> 6;       // 0..7
  const int wm = wv >> 2;        // 0..1  (A half = wm)
  const int wn = wv & 3;         // 0..3  (B half = wn>>1, sub = wn&1)

  // XCD swizzle: 512 blocks, 512 % 8 == 0 -> bijective
  int bid = (blockIdx.x & 7) * 64 + (blockIdx.x >> 3);
  const int bm = bid >> 5;       // 0..15
  const int bn = bid & 31;       // 0..31

  const char* a_src = At + (size_t)bm * (NT_K * 2 * PANB) + tid * 16;
  const char* b_src = Bt + (size_t)bn * (NT_K * 2 * PANB) + tid * 16;
  char* a_lds = lds + tid * 16;
  char* b_lds = lds + LDSB + tid * 16;

  // per-lane ds_read byte offsets (XOR-swizzled)
  const int l15 = lane & 15;
  const int l7  = lane & 7;
  const int q   = lane >> 4;
  int offk[2];
  offk[0] = l15 * 128 + (((0 + q) ^ l7) << 4);
  offk[1] = l15 * 128 + (((4 + q) ^ l7) << 4);

  const char* apan_base = lds + wm * PANB;                 // + parity*2*PANB
  const char* bpan_base = lds + LDSB + (wn >> 1) * PANB;
  const int bcol = (wn & 1) * 8192;

  f32x4 acc[8][4] = {};
  bf16x8 af[4][2];       // current A half (a0 then a1, then a0(t+1))
  bf16x8 bn0[2][2];      // B cols [0..31] of wave quarter
  bf16x8 bn1[2][2];      // B cols [32..63]

  // ---- prologue: B(0)h0,h1  A(0)h0,h1  B(1)h0,h1 ----
  stage(b_src + 0 * PANB, b_lds + 0 * PANB);
  stage(b_src + 1 * PANB, b_lds + 1 * PANB);
  stage(a_src + 0 * PANB, a_lds + 0 * PANB);
  stage(a_src + 1 * PANB, a_lds + 1 * PANB);
  stage(b_src + 2 * PANB, b_lds + 2 * PANB);
  stage(b_src + 3 * PANB, b_lds + 3 * PANB);
  asm volatile("s_waitcnt vmcnt(4)" ::: "memory");   // A(0)+B(0) landed
  __builtin_amdgcn_s_barrier();

  // prologue reads: a0(0), n0(0)
#pragma unroll
  for (int mi = 0; mi < 4; ++mi)
#pragma unroll
    for (int ks = 0; ks < 2; ++ks)
      af[mi][ks] = *(const bf16x8*)(apan_base + mi * 2048 + offk[ks]);
#pragma unroll
  for (int nj = 0; nj < 2; ++nj)
#pragma unroll
    for (int ks = 0; ks < 2; ++ks)
      bn0[nj][ks] = *(const bf16x8*)(bpan_base + bcol + nj * 2048 + offk[ks]);

#pragma unroll 2
  for (int t = 0; t < NT_K; ++t) {
    const int par = (t & 1) * 2;
    const char* apan  = apan_base + par * PANB;
    const char* bpan  = bpan_base + par * PANB;
    const char* apanN = apan_base + (2 - par) * PANB;
    const char* bpanN = bpan_base + (2 - par) * PANB;

    // ===== ph0: a0 x n0 -> acc[0..3][0..1]; shadow: stage Ah0(t+1), read n1(t) =====
    __builtin_amdgcn_s_setprio(1);
#pragma unroll
    for (int mi = 0; mi < 4; ++mi)
#pragma unroll
      for (int nj = 0; nj < 2; ++nj)
#pragma unroll
        for (int ks = 0; ks < 2; ++ks)
          acc[mi][nj] = __builtin_amdgcn_mfma_f32_16x16x32_bf16(
              af[mi][ks], bn0[nj][ks], acc[mi][nj], 0, 0, 0);
    __builtin_amdgcn_s_setprio(0);
    if (t + 1 < NT_K)
      stage(a_src + (size_t)(t + 1) * 2 * PANB, a_lds + (2 - par) * PANB);
#pragma unroll
    for (int nj = 0; nj < 2; ++nj)
#pragma unroll
      for (int ks = 0; ks < 2; ++ks)
        bn1[nj][ks] = *(const bf16x8*)(bpan + bcol + 4096 + nj * 2048 + offk[ks]);
    __builtin_amdgcn_s_barrier();

    // ===== ph1: a0 x n1 -> acc[0..3][2..3]; shadow: stage Ah1(t+1), read a1(t) =====
    __builtin_amdgcn_s_setprio(1);
#pragma unroll
    for (int mi = 0; mi < 4; ++mi)
#pragma unroll
      for (int nj = 0; nj < 2; ++nj)
#pragma unroll
        for (int ks = 0; ks < 2; ++ks)
          acc[mi][2 + nj] = __builtin_amdgcn_mfma_f32_16x16x32_bf16(
              af[mi][ks], bn1[nj][ks], acc[mi][2 + nj], 0, 0, 0);
    __builtin_amdgcn_s_setprio(0);
    if (t + 1 < NT_K)
      stage(a_src + (size_t)(t + 1) * 2 * PANB + PANB, a_lds + (3 - par) * PANB);
#pragma unroll
    for (int mi = 0; mi < 4; ++mi)
#pragma unroll
      for (int ks = 0; ks < 2; ++ks)
        af[mi][ks] = *(const bf16x8*)(apan + 8192 + mi * 2048 + offk[ks]);
    __builtin_amdgcn_s_barrier();

    // ===== ph2: a1 x n1 -> acc[4..7][2..3]; shadow: stage Bh0(t+2); vmcnt =====
    __builtin_amdgcn_s_setprio(1);
#pragma unroll
    for (int mi = 0; mi < 4; ++mi)
#pragma unroll
      for (int nj = 0; nj < 2; ++nj)
#pragma unroll
        for (int ks = 0; ks < 2; ++ks)
          acc[4 + mi][2 + nj] = __builtin_amdgcn_mfma_f32_16x16x32_bf16(
              af[mi][ks], bn1[nj][ks], acc[4 + mi][2 + nj], 0, 0, 0);
    __builtin_amdgcn_s_setprio(0);
    if (t + 2 < NT_K)
      stage(b_src + (size_t)(t + 2) * 2 * PANB, b_lds + par * PANB);
    // steady state: newest 2 loads (= Bh0(t+2) stage) may stay in flight;
    // everything through A(t+1)+B(t+1) certified landed.
    // Last two tiles have no ph2 stage -> the queue tail is A1(t+1)'s loads,
    // which ph1(t+1) will ds_read: must drain fully (the R3 race).
    if (t < NT_K - 2)
      asm volatile("s_waitcnt vmcnt(2)" ::: "memory");
    else
      asm volatile("s_waitcnt vmcnt(0)" ::: "memory");
    __builtin_amdgcn_s_barrier();

    // ===== ph3: a1 x n0 -> acc[4..7][0..1]; shadow: stage Bh1(t+2),
    //           read a0(t+1), n0(t+1) =====
    __builtin_amdgcn_s_setprio(1);
#pragma unroll
    for (int mi = 0; mi < 4; ++mi)
#pragma unroll
      for (int nj = 0; nj < 2; ++nj)
#pragma unroll
        for (int ks = 0; ks < 2; ++ks)
          acc[4 + mi][nj] = __builtin_amdgcn_mfma_f32_16x16x32_bf16(
              af[mi][ks], bn0[nj][ks], acc[4 + mi][nj], 0, 0, 0);
    __builtin_amdgcn_s_setprio(0);
    if (t + 2 < NT_K)
      stage(b_src + (size_t)(t + 2) * 2 * PANB + PANB, b_lds + (par + 1) * PANB);
    if (t + 1 < NT_K) {
#pragma unroll
      for (int mi = 0; mi < 4; ++mi)
#pragma unroll
        for (int ks = 0; ks < 2; ++ks)
          af[mi][ks] = *(const bf16x8*)(apanN + mi * 2048 + offk[ks]);
#pragma unroll
      for (int nj = 0; nj < 2; ++nj)
#pragma unroll
        for (int ks = 0; ks < 2; ++ks)
          bn0[nj][ks] = *(const bf16x8*)(bpanN + bcol + nj * 2048 + offk[ks]);
    }
    __builtin_amdgcn_s_barrier();
  }

  // ---- epilogue: bf16 C-write (layout m89/m91: col=lane&15, row=(lane>>4)*4+j) ----
  const int crow0 = (lane >> 4) * 4;
  const int ccol  = lane & 15;
#pragma unroll
  for (int mi = 0; mi < 8; ++mi)
#pragma unroll
    for (int nj = 0; nj < 4; ++nj)
#pragma unroll
      for (int j = 0; j < 4; ++j) {
        int row = bm * 256 + wm * 128 + mi * 16 + crow0 + j;
        int col = bn * 256 + wn * 64 + nj * 16 + ccol;
        pre[(size_t)row * N4 + col] = (bf16)acc[mi][nj][j];
      }
}

// ---------- fused pointwise + GroupNorm: one block per batch row ----------
__global__ __launch_bounds__(256) void fusedpost(
    const bf16* __restrict__ pre,
    const float* __restrict__ bi, const float* __restrict__ bfp,
    const float* __restrict__ bz, const float* __restrict__ bo,
    const float* __restrict__ c_prev, const float* __restrict__ n_prev,
    const float* __restrict__ m_prev,
    const float* __restrict__ gnw, const float* __restrict__ gnb,
    float* __restrict__ out) {
  const int b = blockIdx.x;
  const int t = threadIdx.x;
  const int h0 = t * 8;
  const long PL = (long)B_ * H_;
  const long e = (long)b * H_ + h0;
  const bf16* prow = pre + (size_t)b * N4;

  bf16x8 PI = *(const bf16x8*)(prow + 0 * H_ + h0);
  bf16x8 PF = *(const bf16x8*)(prow + 1 * H_ + h0);
  bf16x8 PZ = *(const bf16x8*)(prow + 2 * H_ + h0);
  bf16x8 PO = *(const bf16x8*)(prow + 3 * H_ + h0);
  f32x4 BI0 = *(const f32x4*)(bi + h0),  BI1 = *(const f32x4*)(bi + h0 + 4);
  f32x4 BF0 = *(const f32x4*)(bfp + h0), BF1 = *(const f32x4*)(bfp + h0 + 4);
  f32x4 BZ0 = *(const f32x4*)(bz + h0),  BZ1 = *(const f32x4*)(bz + h0 + 4);
  f32x4 BO0 = *(const f32x4*)(bo + h0),  BO1 = *(const f32x4*)(bo + h0 + 4);
  f32x4 CP0 = *(const f32x4*)(c_prev + e), CP1 = *(const f32x4*)(c_prev + e + 4);
  f32x4 NP0 = *(const f32x4*)(n_prev + e), NP1 = *(const f32x4*)(n_prev + e + 4);
  f32x4 MP0 = *(const f32x4*)(m_prev + e), MP1 = *(const f32x4*)(m_prev + e + 4);

  float cs[8], og[8];
  f32x4 C0, C1, N0, N1, M0, M1;
  float sum = 0.f, sq = 0.f;
#pragma unroll
  for (int j = 0; j < 8; ++j) {
    float pi = (float)PI[j] + ((j < 4) ? BI0[j] : BI1[j - 4]);
    float pf = (float)PF[j] + ((j < 4) ? BF0[j] : BF1[j - 4]);
    float pz = (float)PZ[j] + ((j < 4) ? BZ0[j] : BZ1[j - 4]);
    float po = (float)PO[j] + ((j < 4) ? BO0[j] : BO1[j - 4]);
    float cp = (j < 4) ? CP0[j] : CP1[j - 4];
    float np = (j < 4) ? NP0[j] : NP1[j - 4];
    float mp = (j < 4) ? MP0[j] : MP1[j - 4];
    float ig = sigm(pi);
    float fg = sigm(pf);
    float zg = tanh_fast(pz);
    og[j] = sigm(po);
    float m = fmaxf(fg * mp, ig);
    float c = fg * cp + ig * zg;
    float n = fg * np + ig;
    if (j < 4) { C0[j] = c; N0[j] = n; M0[j] = m; }
    else       { C1[j-4] = c; N1[j-4] = n; M1[j-4] = m; }
    float v = c / n;
    cs[j] = v;
    sum += v;
    sq  += v * v;
  }
  *(f32x4*)(out + PL * 1 + e) = C0; *(f32x4*)(out + PL * 1 + e + 4) = C1;
  *(f32x4*)(out + PL * 2 + e) = N0; *(f32x4*)(out + PL * 2 + e + 4) = N1;
  *(f32x4*)(out + PL * 3 + e) = M0; *(f32x4*)(out + PL * 3 + e + 4) = M1;

#pragma unroll
  for (int off = 1; off < 64; off <<= 1) {
    sum += __shfl_xor(sum, off);
    sq  += __shfl_xor(sq, off);
  }
  __shared__ float s1[4], s2[4];
  const int wv = t >> 6, lane = t & 63;
  if (lane == 0) { s1[wv] = sum; s2[wv] = sq; }
  __syncthreads();
  sum = s1[0] + s1[1] + s1[2] + s1[3];
  sq  = s2[0] + s2[1] + s2[2] + s2[3];
  const float mu  = sum * (1.0f / H_);
  const float var = sq * (1.0f / H_) - mu * mu;
  const float rinv = rsqrtf(var + EPSGN);

  f32x4 GW0 = *(const f32x4*)(gnw + h0), GW1 = *(const f32x4*)(gnw + h0 + 4);
  f32x4 GB0 = *(const f32x4*)(gnb + h0), GB1 = *(const f32x4*)(gnb + h0 + 4);
  f32x4 Hh0, Hh1;
#pragma unroll
  for (int j = 0; j < 8; ++j) {
    float gw = (j < 4) ? GW0[j] : GW1[j - 4];
    float gb = (j < 4) ? GB0[j] : GB1[j - 4];
    float g = (cs[j] - mu) * rinv * gw + gb;
    float hv = og[j] * tanh_fast(g);
    if (j < 4) Hh0[j] = hv; else Hh1[j - 4] = hv;
  }
  *(f32x4*)(out + e) = Hh0;
  *(f32x4*)(out + e + 4) = Hh1;
}

// ---------- launch ----------
extern "C" void kernel_launch(void* const* d_in, const int* in_sizes, int n_in,
                              void* d_out, int out_size, void* d_ws, size_t ws_size,
                              hipStream_t stream) {
  const float* x      = (const float*)d_in[0];
  const float* h_prev = (const float*)d_in[1];
  const float* c_prev = (const float*)d_in[2];
  const float* n_prev = (const float*)d_in[3];
  const float* m_prev = (const float*)d_in[4];
  const float* Wi = (const float*)d_in[5];
  const float* Wf = (const float*)d_in[6];
  const float* Wz = (const float*)d_in[7];
  const float* Wo = (const float*)d_in[8];
  const float* bi = (const float*)d_in[9];
  const float* bf = (const float*)d_in[10];
  const float* bz = (const float*)d_in[11];
  const float* bo = (const float*)d_in[12];
  const float* Ri = (const float*)d_in[13];
  const float* Rf = (const float*)d_in[14];
  const float* Rz = (const float*)d_in[15];
  const float* Ro = (const float*)d_in[16];
  const float* gnw = (const float*)d_in[17];
  const float* gnb = (const float*)d_in[18];

  char* ws = (char*)d_ws;
  char* At = ws;                                             // 24 MiB
  char* Bt = ws + (size_t)B_ * K_ * 2;                       // 48 MiB
  bf16* pre = (bf16*)(ws + (size_t)B_ * K_ * 2 + (size_t)N4 * K_ * 2);  // 64 MiB
  float* out = (float*)d_out;

  hipFuncSetAttribute((const void*)gemm8,
                      hipFuncAttributeMaxDynamicSharedMemorySize, 131072);

  convA<<<((size_t)B_ * K_ / 8) / 256, 256, 0, stream>>>(x, h_prev, At);
  convB<<<((size_t)N4 * K_ / 8) / 256, 256, 0, stream>>>(Wi, Wf, Wz, Wo,
                                                         Ri, Rf, Rz, Ro, Bt);
  gemm8<<<512, 512, 131072, stream>>>(At, Bt, pre);
  fusedpost<<<B_, 256, 0, stream>>>(pre, bi, bf, bz, bo,
                                    c_prev, n_prev, m_prev, gnw, gnb, out);
}